// Round 1
// baseline (38578.171 us; speedup 1.0000x reference)
//
#include <hip/hip_runtime.h>
#include <hip/hip_bf16.h>

// LSTM: B=128, T=1024, D=H=768.
// Strategy:
//   P1: transpose+convert x[B][T][D] f32 -> xT[T][B][D] bf16 (ws)
//   P2: build per-WG weight slices (W_hh | W_ih), rows permuted so each WG's
//       32 gate rows = 4 gates x 8 h-cols, K-chunks XOR-swizzled for LDS
//   P3: bias_ih+bias_hh (permuted), h0 -> bf16 ping buffer, zero flags
//   K : persistent recurrent kernel, 96 WGs x 4 waves; per-band (32 batch
//       rows) dataflow sync via ready-flags; fused x-projection computed in
//       the shadow of the flag wait; 32x32x16 bf16 MFMA, f32 accum.

typedef __attribute__((ext_vector_type(8))) short short8v;   // 8 bf16 = 4 VGPR
typedef __attribute__((ext_vector_type(16))) float f32x16;   // 32x32 acc

constexpr int B_ = 128, T_ = 1024, D_ = 768, H_ = 768;
constexpr int NWG = 96;          // j-groups (8 h-cols each)

constexpr size_t FLAGS_OFF = 0;                        // 4 bands * 96 ints
constexpr size_t HB_OFF    = 4096;                     // 2*128*768 bf16 = 393216 B
constexpr size_t BIAS_OFF  = HB_OFF + 393216;          // 3072 f32 = 12288 B
constexpr size_t WC_OFF    = BIAS_OFF + 12288;         // 96*2*32*768 bf16 = 9437184 B
constexpr size_t XT_OFF    = WC_OFF + 9437184;         // 1024*128*768 bf16 = 201326592 B
constexpr size_t WS_NEED   = XT_OFF + 201326592;       // ~211.2 MB

__device__ __forceinline__ unsigned short f2bf(float f) {
  union { float f; unsigned u; } v; v.f = f;
  unsigned r = v.u + 0x7FFF + ((v.u >> 16) & 1);       // RNE
  return (unsigned short)(r >> 16);
}
__device__ __forceinline__ float sigmf(float x) { return 1.0f / (1.0f + __expf(-x)); }
__device__ __forceinline__ float tanhf_(float x) {
  float ax = fabsf(x);
  float e = __expf(-2.0f * ax);
  float t = (1.0f - e) / (1.0f + e);
  return copysignf(t, x);
}

// ---------------- P1: x -> xT (bf16, [t*128+b][768]) ----------------
__global__ void k_xT(const float* __restrict__ x, unsigned short* __restrict__ xT) {
  int row  = blockIdx.x * 4 + (threadIdx.x >> 6);      // out row = t*128 + b
  int lane = threadIdx.x & 63;
  int t = row >> 7, b = row & 127;
  const float* src = x + ((size_t)b * T_ + t) * D_;
  unsigned short* dst = xT + (size_t)row * D_;
  #pragma unroll
  for (int p = 0; p < 3; ++p) {
    int d = p * 256 + lane * 4;
    float4 v = *(const float4*)(src + d);
    ushort4 o = {f2bf(v.x), f2bf(v.y), f2bf(v.z), f2bf(v.w)};
    *(ushort4*)(dst + d) = o;
  }
}

// ---------------- P2: weight slices, swizzled ----------------
// Wc chunk id = wj*6144 + src*3072 + r*96 + kcp ; each chunk = 8 bf16 (16B)
// LDS image per WG: [src(2)][r(32)][kc'(96)] ; kc' = kc ^ (r&15)
__global__ void k_prep_w(const float* __restrict__ wih, const float* __restrict__ whh,
                         unsigned short* __restrict__ Wc) {
  int id  = blockIdx.x * 256 + threadIdx.x;            // exactly 589824
  int wj  = id / 6144;
  int rem = id - wj * 6144;
  int src = rem / 3072; rem -= src * 3072;
  int r   = rem / 96;
  int kcp = rem - r * 96;
  int kc  = kcp ^ (r & 15);
  int grow = (r >> 3) * H_ + wj * 8 + (r & 7);         // gate*768 + j
  const float* W = (src == 0) ? whh : wih;
  const float* p = W + (size_t)grow * D_ + kc * 8;
  float4 v0 = *(const float4*)p;
  float4 v1 = *(const float4*)(p + 4);
  ushort4 o0 = {f2bf(v0.x), f2bf(v0.y), f2bf(v0.z), f2bf(v0.w)};
  ushort4 o1 = {f2bf(v1.x), f2bf(v1.y), f2bf(v1.z), f2bf(v1.w)};
  *(ushort4*)(Wc + (size_t)id * 8)     = o0;
  *(ushort4*)(Wc + (size_t)id * 8 + 4) = o1;
}

// ---------------- P3: bias, h0->bf16, flags ----------------
__global__ void k_prep_s(const float* __restrict__ h0,
                         const float* __restrict__ bih, const float* __restrict__ bhh,
                         unsigned short* __restrict__ hb, float* __restrict__ bias_c,
                         int* __restrict__ flags) {
  int id = blockIdx.x * 256 + threadIdx.x;             // exactly 98304
  hb[id] = f2bf(h0[id]);                               // ping buffer 0
  if (id < 3072) {
    int wj = id >> 5, r = id & 31;
    int grow = (r >> 3) * H_ + wj * 8 + (r & 7);
    bias_c[id] = bih[grow] + bhh[grow];
  }
  if (id < 384) flags[id] = 0;
}

// ---------------- main recurrent kernel ----------------
__device__ __forceinline__ void gemm_phase(f32x16& acc,
                                           const unsigned short* __restrict__ a_base,
                                           const unsigned short* wl, int wrow_byte,
                                           int sw, int kh) {
  #pragma unroll
  for (int f = 0; f < 48; ++f) {
    short8v a = *reinterpret_cast<const short8v*>(a_base + f * 16 + kh * 8);
    int kc = (2 * f + kh) ^ sw;
    short8v b = *reinterpret_cast<const short8v*>(
        reinterpret_cast<const char*>(wl) + wrow_byte + kc * 16);
    acc = __builtin_amdgcn_mfma_f32_32x32x16_bf16(a, b, acc, 0, 0, 0);
  }
}

__launch_bounds__(256, 1)
__global__ void k_lstm(const unsigned short* __restrict__ xT,
                       const unsigned short* __restrict__ Wc,
                       const float* __restrict__ bias_c,
                       const float* __restrict__ c0,
                       unsigned short* __restrict__ hb,   // [2][128][768] bf16
                       int* flags,                        // [4][96]
                       float* __restrict__ out,           // [128][1024][768]
                       float* __restrict__ hT,
                       float* __restrict__ cT) {
  __shared__ __align__(16) unsigned short Wl[2 * 32 * 768];   // 96 KB (swizzled)
  __shared__ float gb[4][32][33];                             // per-wave gate tile
  __shared__ float bias_l[32];

  const int wj   = blockIdx.x;
  const int tid  = threadIdx.x;
  const int wave = tid >> 6;          // band: batch rows wave*32..+32
  const int lane = tid & 63;
  const int col  = lane & 31;         // A-row-in-band / B-col / C-col
  const int kh   = lane >> 5;
  const int sw   = col & 15;

  { // stage weight slices (pre-swizzled in global -> linear copy)
    const short8v* s = (const short8v*)(Wc + (size_t)wj * 49152);
    short8v* d = (short8v*)Wl;
    for (int i = tid; i < 6144; i += 256) d[i] = s[i];
    if (tid < 32) bias_l[tid] = bias_c[wj * 32 + tid];
  }
  __syncthreads();

  const int bg = wave * 32 + col;     // global batch row
  const int jq = 4 * kh;
  const int jg = wj * 8 + jq;         // global h col base (4 cols per lane)

  float c_r[4];
  {
    float4 v = *(const float4*)(c0 + (size_t)bg * H_ + jg);
    c_r[0] = v.x; c_r[1] = v.y; c_r[2] = v.z; c_r[3] = v.w;
  }

  const int wrow0 = col * 1536;             // W_hh row base (bytes)
  const int wrow1 = (32 + col) * 1536;      // W_ih row base

  int* fb = flags + wave * 96;
  const int i1 = lane;
  const int i2 = 64 + (lane & 31);

  f32x16 acc;
  { // phase X for t=0 (acc starts at bias)
    float b0 = bias_l[col];
    #pragma unroll
    for (int q = 0; q < 16; ++q) acc[q] = b0;
    gemm_phase(acc, xT + (size_t)bg * D_, Wl, wrow1, sw, kh);
  }

  for (int t = 0; t < T_; ++t) {
    if (t > 0) {
      for (;;) {  // relaxed agent-scope polls bypass local L2 (no stale spin)
        int v0 = __hip_atomic_load(fb + i1, __ATOMIC_RELAXED, __HIP_MEMORY_SCOPE_AGENT);
        int v1 = __hip_atomic_load(fb + i2, __ATOMIC_RELAXED, __HIP_MEMORY_SCOPE_AGENT);
        if (__all((v0 >= t) && (v1 >= t))) break;
        __builtin_amdgcn_s_sleep(8);
      }
      __threadfence();  // acquire: invalidate L1/L2 before reading h_t
    }

    // phase H: accumulate h_t @ W_hh^T into acc
    gemm_phase(acc, hb + (size_t)(t & 1) * (B_ * H_) + (size_t)bg * H_,
               Wl, wrow0, sw, kh);

    // acc -> LDS (wave-private), transposed gather for gating
    #pragma unroll
    for (int q = 0; q < 16; ++q) {
      int m = (q & 3) + 8 * (q >> 2) + 4 * kh;
      gb[wave][m][col] = acc[q];
    }
    asm volatile("s_waitcnt lgkmcnt(0)" ::: "memory");

    float hnew[4];
    #pragma unroll
    for (int q = 0; q < 4; ++q) {
      int jl = jq + q;
      float gi = gb[wave][col][jl];
      float gf = gb[wave][col][8 + jl];
      float gg = gb[wave][col][16 + jl];
      float go = gb[wave][col][24 + jl];
      float cn = sigmf(gf) * c_r[q] + sigmf(gi) * tanhf_(gg);
      c_r[q] = cn;
      hnew[q] = sigmf(go) * tanhf_(cn);
    }

    ushort4 hv = {f2bf(hnew[0]), f2bf(hnew[1]), f2bf(hnew[2]), f2bf(hnew[3])};
    *(ushort4*)(hb + (size_t)((t + 1) & 1) * (B_ * H_) + (size_t)bg * H_ + jg) = hv;
    float4 ov = make_float4(hnew[0], hnew[1], hnew[2], hnew[3]);
    *(float4*)(out + ((size_t)bg * T_ + t) * H_ + jg) = ov;
    if (t == T_ - 1) {
      *(float4*)(hT + (size_t)bg * H_ + jg) = ov;
      float4 cv = make_float4(c_r[0], c_r[1], c_r[2], c_r[3]);
      *(float4*)(cT + (size_t)bg * H_ + jg) = cv;
    }

    __threadfence();  // release: drain stores + writeback L2
    if (lane == 0)
      __hip_atomic_store(fb + wj, t + 1, __ATOMIC_RELEASE, __HIP_MEMORY_SCOPE_AGENT);

    // phase X for t+1, in the shadow of other producers' work
    if (t + 1 < T_) {
      float b0 = bias_l[col];
      #pragma unroll
      for (int q = 0; q < 16; ++q) acc[q] = b0;
      gemm_phase(acc, xT + ((size_t)(t + 1) * B_ + bg) * D_, Wl, wrow1, sw, kh);
    }
  }
}

extern "C" void kernel_launch(void* const* d_in, const int* in_sizes, int n_in,
                              void* d_out, int out_size, void* d_ws, size_t ws_size,
                              hipStream_t stream) {
  const float* x   = (const float*)d_in[0];
  const float* h0  = (const float*)d_in[1];
  const float* c0  = (const float*)d_in[2];
  const float* wih = (const float*)d_in[3];
  const float* whh = (const float*)d_in[4];
  const float* bih = (const float*)d_in[5];
  const float* bhh = (const float*)d_in[6];

  float* out = (float*)d_out;
  float* hT  = out + (size_t)B_ * T_ * H_;
  float* cT  = hT + (size_t)B_ * H_;

  if (ws_size < WS_NEED) return;  // visible failure instead of OOB corruption

  char* ws = (char*)d_ws;
  int*            flags = (int*)(ws + FLAGS_OFF);
  unsigned short* hb    = (unsigned short*)(ws + HB_OFF);
  float*          biasc = (float*)(ws + BIAS_OFF);
  unsigned short* Wc    = (unsigned short*)(ws + WC_OFF);
  unsigned short* xTp   = (unsigned short*)(ws + XT_OFF);

  k_xT<<<dim3((B_ * T_) / 4), dim3(256), 0, stream>>>(x, xTp);
  k_prep_w<<<dim3(589824 / 256), dim3(256), 0, stream>>>(wih, whh, Wc);
  k_prep_s<<<dim3((B_ * H_) / 256), dim3(256), 0, stream>>>(h0, bih, bhh, hb, biasc, flags);
  k_lstm<<<dim3(NWG), dim3(256), 0, stream>>>(xTp, Wc, biasc, c0, hb, flags, out, hT, cT);
}

// Round 2
// 22600.894 us; speedup vs baseline: 1.7069x; 1.7069x over previous
//
#include <hip/hip_runtime.h>
#include <hip/hip_bf16.h>

// LSTM: B=128, T=1024, D=H=768.
// Strategy:
//   P1: transpose+convert x[B][T][D] f32 -> xT[T][B][D] bf16 (ws)
//   P2: build per-WG weight slices (W_hh | W_ih), rows permuted so each WG's
//       32 gate rows = 4 gates x 8 h-cols, K-chunks XOR-swizzled for LDS
//   P3: bias_ih+bias_hh (permuted), h0 -> bf16 ping buffer, zero flags
//   K : persistent recurrent kernel, 96 WGs x 4 waves; per-band (32 batch
//       rows) dataflow sync via ready-flags; fused x-projection computed in
//       the shadow of the flag wait; 32x32x16 bf16 MFMA, f32 accum.
// R2 change: NO cache-maintenance fences (buffer_wbl2/buffer_inv were 38us/step).
//   h exchange + flags use relaxed agent-scope atomics (sc1: write-through /
//   read-through the coherence point); release = s_waitcnt vmcnt(0) + relaxed
//   flag store; out stores moved after the release.

typedef __attribute__((ext_vector_type(8))) short short8v;   // 8 bf16 = 4 VGPR
typedef __attribute__((ext_vector_type(16))) float f32x16;   // 32x32 acc

constexpr int B_ = 128, T_ = 1024, D_ = 768, H_ = 768;
constexpr int NWG = 96;          // j-groups (8 h-cols each)

constexpr size_t FLAGS_OFF = 0;                        // 4 bands * 96 ints
constexpr size_t HB_OFF    = 4096;                     // 2*128*768 bf16 = 393216 B
constexpr size_t BIAS_OFF  = HB_OFF + 393216;          // 3072 f32 = 12288 B
constexpr size_t WC_OFF    = BIAS_OFF + 12288;         // 96*2*32*768 bf16 = 9437184 B
constexpr size_t XT_OFF    = WC_OFF + 9437184;         // 1024*128*768 bf16 = 201326592 B
constexpr size_t WS_NEED   = XT_OFF + 201326592;       // ~211.2 MB

__device__ __forceinline__ unsigned short f2bf(float f) {
  union { float f; unsigned u; } v; v.f = f;
  unsigned r = v.u + 0x7FFF + ((v.u >> 16) & 1);       // RNE
  return (unsigned short)(r >> 16);
}
__device__ __forceinline__ float sigmf(float x) { return 1.0f / (1.0f + __expf(-x)); }
__device__ __forceinline__ float tanhf_(float x) {
  float ax = fabsf(x);
  float e = __expf(-2.0f * ax);
  float t = (1.0f - e) / (1.0f + e);
  return copysignf(t, x);
}

// ---------------- P1: x -> xT (bf16, [t*128+b][768]) ----------------
__global__ void k_xT(const float* __restrict__ x, unsigned short* __restrict__ xT) {
  int row  = blockIdx.x * 4 + (threadIdx.x >> 6);      // out row = t*128 + b
  int lane = threadIdx.x & 63;
  int t = row >> 7, b = row & 127;
  const float* src = x + ((size_t)b * T_ + t) * D_;
  unsigned short* dst = xT + (size_t)row * D_;
  #pragma unroll
  for (int p = 0; p < 3; ++p) {
    int d = p * 256 + lane * 4;
    float4 v = *(const float4*)(src + d);
    ushort4 o = {f2bf(v.x), f2bf(v.y), f2bf(v.z), f2bf(v.w)};
    *(ushort4*)(dst + d) = o;
  }
}

// ---------------- P2: weight slices, swizzled ----------------
// Wc chunk id = wj*6144 + src*3072 + r*96 + kcp ; each chunk = 8 bf16 (16B)
// LDS image per WG: [src(2)][r(32)][kc'(96)] ; kc' = kc ^ (r&15)
__global__ void k_prep_w(const float* __restrict__ wih, const float* __restrict__ whh,
                         unsigned short* __restrict__ Wc) {
  int id  = blockIdx.x * 256 + threadIdx.x;            // exactly 589824
  int wj  = id / 6144;
  int rem = id - wj * 6144;
  int src = rem / 3072; rem -= src * 3072;
  int r   = rem / 96;
  int kcp = rem - r * 96;
  int kc  = kcp ^ (r & 15);
  int grow = (r >> 3) * H_ + wj * 8 + (r & 7);         // gate*768 + j
  const float* W = (src == 0) ? whh : wih;
  const float* p = W + (size_t)grow * D_ + kc * 8;
  float4 v0 = *(const float4*)p;
  float4 v1 = *(const float4*)(p + 4);
  ushort4 o0 = {f2bf(v0.x), f2bf(v0.y), f2bf(v0.z), f2bf(v0.w)};
  ushort4 o1 = {f2bf(v1.x), f2bf(v1.y), f2bf(v1.z), f2bf(v1.w)};
  *(ushort4*)(Wc + (size_t)id * 8)     = o0;
  *(ushort4*)(Wc + (size_t)id * 8 + 4) = o1;
}

// ---------------- P3: bias, h0->bf16, flags ----------------
__global__ void k_prep_s(const float* __restrict__ h0,
                         const float* __restrict__ bih, const float* __restrict__ bhh,
                         unsigned short* __restrict__ hb, float* __restrict__ bias_c,
                         int* __restrict__ flags) {
  int id = blockIdx.x * 256 + threadIdx.x;             // exactly 98304
  hb[id] = f2bf(h0[id]);                               // ping buffer 0
  if (id < 3072) {
    int wj = id >> 5, r = id & 31;
    int grow = (r >> 3) * H_ + wj * 8 + (r & 7);
    bias_c[id] = bih[grow] + bhh[grow];
  }
  if (id < 384) flags[id] = 0;
}

// ---------------- main recurrent kernel ----------------
// BYPASS=true: A-fragments read via relaxed agent-scope atomic loads
// (global_load_dwordx2 sc1 -> served at the coherence point, never stale).
template <bool BYPASS>
__device__ __forceinline__ void gemm_phase(f32x16& acc,
                                           const unsigned short* __restrict__ a_base,
                                           const unsigned short* wl, int wrow_byte,
                                           int sw, int kh) {
  #pragma unroll
  for (int f = 0; f < 48; ++f) {
    short8v a;
    if constexpr (BYPASS) {
      union { unsigned long long u[2]; short8v v; } cv;
      const unsigned long long* p =
          reinterpret_cast<const unsigned long long*>(a_base + f * 16 + kh * 8);
      cv.u[0] = __hip_atomic_load(p,     __ATOMIC_RELAXED, __HIP_MEMORY_SCOPE_AGENT);
      cv.u[1] = __hip_atomic_load(p + 1, __ATOMIC_RELAXED, __HIP_MEMORY_SCOPE_AGENT);
      a = cv.v;
    } else {
      a = *reinterpret_cast<const short8v*>(a_base + f * 16 + kh * 8);
    }
    int kc = (2 * f + kh) ^ sw;
    short8v b = *reinterpret_cast<const short8v*>(
        reinterpret_cast<const char*>(wl) + wrow_byte + kc * 16);
    acc = __builtin_amdgcn_mfma_f32_32x32x16_bf16(a, b, acc, 0, 0, 0);
  }
}

__launch_bounds__(256, 1)
__global__ void k_lstm(const unsigned short* __restrict__ xT,
                       const unsigned short* __restrict__ Wc,
                       const float* __restrict__ bias_c,
                       const float* __restrict__ c0,
                       unsigned short* __restrict__ hb,   // [2][128][768] bf16
                       int* flags,                        // [4][96]
                       float* __restrict__ out,           // [128][1024][768]
                       float* __restrict__ hT,
                       float* __restrict__ cT) {
  __shared__ __align__(16) unsigned short Wl[2 * 32 * 768];   // 96 KB (swizzled)
  __shared__ float gb[4][32][33];                             // per-wave gate tile
  __shared__ float bias_l[32];

  const int wj   = blockIdx.x;
  const int tid  = threadIdx.x;
  const int wave = tid >> 6;          // band: batch rows wave*32..+32
  const int lane = tid & 63;
  const int col  = lane & 31;         // A-row-in-band / B-col / C-col
  const int kh   = lane >> 5;
  const int sw   = col & 15;

  { // stage weight slices (pre-swizzled in global -> linear copy)
    const short8v* s = (const short8v*)(Wc + (size_t)wj * 49152);
    short8v* d = (short8v*)Wl;
    for (int i = tid; i < 6144; i += 256) d[i] = s[i];
    if (tid < 32) bias_l[tid] = bias_c[wj * 32 + tid];
  }
  __syncthreads();

  const int bg = wave * 32 + col;     // global batch row
  const int jq = 4 * kh;
  const int jg = wj * 8 + jq;         // global h col base (4 cols per lane)

  float c_r[4];
  {
    float4 v = *(const float4*)(c0 + (size_t)bg * H_ + jg);
    c_r[0] = v.x; c_r[1] = v.y; c_r[2] = v.z; c_r[3] = v.w;
  }

  const int wrow0 = col * 1536;             // W_hh row base (bytes)
  const int wrow1 = (32 + col) * 1536;      // W_ih row base

  int* fb = flags + wave * 96;
  const int i1 = lane;
  const int i2 = 64 + (lane & 31);

  f32x16 acc;
  { // phase X for t=0 (acc starts at bias)
    float b0 = bias_l[col];
    #pragma unroll
    for (int q = 0; q < 16; ++q) acc[q] = b0;
    gemm_phase<false>(acc, xT + (size_t)bg * D_, Wl, wrow1, sw, kh);
  }

  for (int t = 0; t < T_; ++t) {
    if (t > 0) {
      for (;;) {  // relaxed agent-scope polls read the coherence point
        int v0 = __hip_atomic_load(fb + i1, __ATOMIC_RELAXED, __HIP_MEMORY_SCOPE_AGENT);
        int v1 = __hip_atomic_load(fb + i2, __ATOMIC_RELAXED, __HIP_MEMORY_SCOPE_AGENT);
        if (__all((v0 >= t) && (v1 >= t))) break;
        __builtin_amdgcn_s_sleep(1);
      }
      asm volatile("" ::: "memory");  // compiler barrier; loads below bypass caches
    }

    // phase H: accumulate h_t @ W_hh^T into acc (bypassing loads)
    gemm_phase<true>(acc, hb + (size_t)(t & 1) * (B_ * H_) + (size_t)bg * H_,
                     Wl, wrow0, sw, kh);

    // acc -> LDS (wave-private), transposed gather for gating
    #pragma unroll
    for (int q = 0; q < 16; ++q) {
      int m = (q & 3) + 8 * (q >> 2) + 4 * kh;
      gb[wave][m][col] = acc[q];
    }
    asm volatile("s_waitcnt lgkmcnt(0)" ::: "memory");

    float hnew[4];
    #pragma unroll
    for (int q = 0; q < 4; ++q) {
      int jl = jq + q;
      float gi = gb[wave][col][jl];
      float gf = gb[wave][col][8 + jl];
      float gg = gb[wave][col][16 + jl];
      float go = gb[wave][col][24 + jl];
      float cn = sigmf(gf) * c_r[q] + sigmf(gi) * tanhf_(gg);
      c_r[q] = cn;
      hnew[q] = sigmf(go) * tanhf_(cn);
    }

    // h exchange: 8B write-through (agent-scope) store, no cache maintenance
    union { ushort4 s; unsigned long long u; } hv;
    hv.s = (ushort4){f2bf(hnew[0]), f2bf(hnew[1]), f2bf(hnew[2]), f2bf(hnew[3])};
    __hip_atomic_store(
        (unsigned long long*)(hb + (size_t)((t + 1) & 1) * (B_ * H_) +
                              (size_t)bg * H_ + jg),
        hv.u, __ATOMIC_RELAXED, __HIP_MEMORY_SCOPE_AGENT);

    // release: h stores acked at coherence point, then relaxed flag store
    asm volatile("s_waitcnt vmcnt(0)" ::: "memory");
    if (lane == 0)
      __hip_atomic_store(fb + wj, t + 1, __ATOMIC_RELAXED, __HIP_MEMORY_SCOPE_AGENT);

    // out stores AFTER the release (off the critical path, normal write-back)
    float4 ov = make_float4(hnew[0], hnew[1], hnew[2], hnew[3]);
    *(float4*)(out + ((size_t)bg * T_ + t) * H_ + jg) = ov;
    if (t == T_ - 1) {
      *(float4*)(hT + (size_t)bg * H_ + jg) = ov;
      float4 cv = make_float4(c_r[0], c_r[1], c_r[2], c_r[3]);
      *(float4*)(cT + (size_t)bg * H_ + jg) = cv;
    }

    // phase X for t+1, in the shadow of other producers' work
    if (t + 1 < T_) {
      float b0 = bias_l[col];
      #pragma unroll
      for (int q = 0; q < 16; ++q) acc[q] = b0;
      gemm_phase<false>(acc, xT + ((size_t)(t + 1) * B_ + bg) * D_, Wl, wrow1, sw, kh);
    }
  }
}

extern "C" void kernel_launch(void* const* d_in, const int* in_sizes, int n_in,
                              void* d_out, int out_size, void* d_ws, size_t ws_size,
                              hipStream_t stream) {
  const float* x   = (const float*)d_in[0];
  const float* h0  = (const float*)d_in[1];
  const float* c0  = (const float*)d_in[2];
  const float* wih = (const float*)d_in[3];
  const float* whh = (const float*)d_in[4];
  const float* bih = (const float*)d_in[5];
  const float* bhh = (const float*)d_in[6];

  float* out = (float*)d_out;
  float* hT  = out + (size_t)B_ * T_ * H_;
  float* cT  = hT + (size_t)B_ * H_;

  if (ws_size < WS_NEED) return;  // visible failure instead of OOB corruption

  char* ws = (char*)d_ws;
  int*            flags = (int*)(ws + FLAGS_OFF);
  unsigned short* hb    = (unsigned short*)(ws + HB_OFF);
  float*          biasc = (float*)(ws + BIAS_OFF);
  unsigned short* Wc    = (unsigned short*)(ws + WC_OFF);
  unsigned short* xTp   = (unsigned short*)(ws + XT_OFF);

  k_xT<<<dim3((B_ * T_) / 4), dim3(256), 0, stream>>>(x, xTp);
  k_prep_w<<<dim3(589824 / 256), dim3(256), 0, stream>>>(wih, whh, Wc);
  k_prep_s<<<dim3((B_ * H_) / 256), dim3(256), 0, stream>>>(h0, bih, bhh, hb, biasc, flags);
  k_lstm<<<dim3(NWG), dim3(256), 0, stream>>>(xTp, Wc, biasc, c0, hb, flags, out, hT, cT);
}